// Round 19
// baseline (164.805 us; speedup 1.0000x reference)
//
#include <hip/hip_runtime.h>
#include <hip/hip_bf16.h>
#include <cstdint>

#define B_SZ   512
#define NLAT   64
#define H_SZ   32
#define G_OI_N 5000
#define K_SZ   64

#define NCHUNK 1250   // chunks of 4 genes (one per wave); logit blocks = 2*NCHUNK
#define RHO_BLOCKS 320

typedef __attribute__((ext_vector_type(8))) short short8v;   // 8 x bf16
typedef __attribute__((ext_vector_type(4))) float float4v;

__device__ __forceinline__ unsigned short f2bf(float x) {
    union { float f; unsigned u; } v; v.f = x;
    unsigned r = v.u + 0x7fff + ((v.u >> 16) & 1);            // RTNE
    return (unsigned short)(r >> 16);
}

// ---------------- Kernel A: h = BN(relu(latent @ W1 + b1))
__global__ __launch_bounds__(256) void mlp_kernel(
    const float* __restrict__ latent, const float* __restrict__ W1,
    const float* __restrict__ b1, const float* __restrict__ gamma,
    const float* __restrict__ beta, const float* __restrict__ mean,
    const float* __restrict__ var, float* __restrict__ hout,
    unsigned short* __restrict__ hbf)
{
    int idx = blockIdx.x * 256 + threadIdx.x;   // 0..16383 = b*32 + j
    int b = idx >> 5;
    int j = idx & 31;
    float acc = 0.f;
    const float4* lp = reinterpret_cast<const float4*>(latent + b * NLAT);
#pragma unroll
    for (int q = 0; q < NLAT / 4; ++q) {
        float4 lv = lp[q];
        acc = fmaf(lv.x, W1[(4 * q + 0) * H_SZ + j], acc);
        acc = fmaf(lv.y, W1[(4 * q + 1) * H_SZ + j], acc);
        acc = fmaf(lv.z, W1[(4 * q + 2) * H_SZ + j], acc);
        acc = fmaf(lv.w, W1[(4 * q + 3) * H_SZ + j], acc);
    }
    acc += b1[j];
    acc = fmaxf(acc, 0.f);
    acc = gamma[j] * (acc - mean[j]) * rsqrtf(var[j] + 1e-5f) + beta[j];
    hout[idx] = acc;
    hbf[idx]  = f2bf(acc);
}

// ---------------- Kernel B+C fused (r18 WIN structure). ONE change vs r18:
// bh moved from blockIdx LSB to MSB — co-resident blocks now cover a
// contiguous gene window of a SINGLE 256-row half, halving the co-temporal
// write-address span (global dispatch-order locality test).
__global__ __launch_bounds__(256) void logit_rho_kernel(
    const unsigned short* __restrict__ hbf, const int* __restrict__ genes,
    const float* __restrict__ lw, float* __restrict__ out,
    const float* __restrict__ hbuf, const float* __restrict__ rw,
    float* __restrict__ rho_out)
{
    __shared__ float lt[4 * 1024];             // 4 waves x 4KB private tiles

    if (blockIdx.x >= 2 * NCHUNK) {
        // ---------- rho path: rho[b,g] = sum_h h[b,h] * rw[genes[g],h]
        const int rb = blockIdx.x - 2 * NCHUNK;   // 0..319
        const int gx = rb % 20;
        const int bx = rb / 20;
        const int g = gx * 256 + threadIdx.x;
        if (g >= G_OI_N) return;
        const size_t gene = (size_t)genes[g];

        float rreg[H_SZ];
        const float4* rp = reinterpret_cast<const float4*>(rw + gene * H_SZ);
#pragma unroll
        for (int q = 0; q < 8; ++q) {
            float4 rv = rp[q];
            rreg[4 * q + 0] = rv.x; rreg[4 * q + 1] = rv.y;
            rreg[4 * q + 2] = rv.z; rreg[4 * q + 3] = rv.w;
        }
        const int b0 = bx * 32;
        for (int b = b0; b < b0 + 32; ++b) {
            const float4* hp = reinterpret_cast<const float4*>(hbuf + b * H_SZ);
            float a0 = 0.f, a1 = 0.f, a2 = 0.f, a3 = 0.f;
#pragma unroll
            for (int q = 0; q < 8; ++q) {
                float4 hv = hp[q];
                a0 = fmaf(hv.x, rreg[4 * q + 0], a0);
                a1 = fmaf(hv.y, rreg[4 * q + 1], a1);
                a2 = fmaf(hv.z, rreg[4 * q + 2], a2);
                a3 = fmaf(hv.w, rreg[4 * q + 3], a3);
            }
            rho_out[(size_t)b * G_OI_N + g] = (a0 + a1) + (a2 + a3);
        }
        return;
    }

    // ---------- logit path (v9): gene-per-wave, private-LDS transpose,
    // zero barriers. bh = MSB of block index (was LSB in r18).
    const int bh    = (blockIdx.x >= NCHUNK) ? 1 : 0;   // 256-row half (MSB)
    const int chunk = blockIdx.x - bh * NCHUNK;         // 0..1249
    const int lane  = threadIdx.x & 63;
    const int w     = threadIdx.x >> 6;        // wave -> own gene
    const int row16 = lane & 15;
    const int kg    = lane >> 4;               // 0..3
    const int b0    = bh * 256;
    char* wt = reinterpret_cast<char*>(lt + w * 1024);

    const int g = chunk * 4 + w;
    const size_t gene = (size_t)genes[g];

    // A-operand (lw): own gene, all 4 kt — loaded once (32 dwords/lane).
    short8v afr[4];
    {
        const float* ap = lw + gene * (size_t)(H_SZ * K_SZ)
                             + (size_t)(kg * 8) * K_SZ + row16;
#pragma unroll
        for (int kt = 0; kt < 4; ++kt)
#pragma unroll
            for (int j = 0; j < 8; ++j)
                afr[kt][j] = (short)f2bf(ap[kt * 16 + (size_t)j * K_SZ]);
    }

    // B-operand (h): 16 m-tiles covering the 256-row half.
    short8v hfr[16];
#pragma unroll
    for (int mt = 0; mt < 16; ++mt)
        hfr[mt] = *reinterpret_cast<const short8v*>(
            hbf + (b0 + mt * 16 + row16) * H_SZ + kg * 8);

    const size_t GK = (size_t)G_OI_N * K_SZ;
    float* og = out + (size_t)g * K_SZ;
    for (int mt = 0; mt < 16; ++mt) {
        // 4 kt MFMAs -> wave-private swizzled LDS tile [16 b-rows][64 k]
#pragma unroll
        for (int kt = 0; kt < 4; ++kt) {
            float4v acc = {0.f, 0.f, 0.f, 0.f};
            acc = __builtin_amdgcn_mfma_f32_16x16x32_bf16(afr[kt], hfr[mt], acc, 0, 0, 0);
            int off = row16 * 256 + kt * 64 + kg * 16;
            off ^= (row16 & 7) << 4;
            *reinterpret_cast<float4v*>(wt + off) = acc;
        }
        // transposed read + store: each instr = 4 rows x 256B contiguous
#pragma unroll
        for (int r2 = 0; r2 < 4; ++r2) {
            const int rrow = 4 * r2 + kg;      // 0..15
            int roff = rrow * 256 + row16 * 16;
            roff ^= (rrow & 7) << 4;
            float4v v = *reinterpret_cast<const float4v*>(wt + roff);
            *reinterpret_cast<float4v*>(
                og + (size_t)(b0 + mt * 16 + rrow) * GK + row16 * 4) = v;
        }
    }
}

extern "C" void kernel_launch(void* const* d_in, const int* in_sizes, int n_in,
                              void* d_out, int out_size, void* d_ws, size_t ws_size,
                              hipStream_t stream)
{
    // Bind inputs by SIZE SIGNATURE (all sizes unique; robust to ordering).
    const float *latent = nullptr, *W1 = nullptr, *lw = nullptr, *rw = nullptr;
    const int* genes = nullptr;
    const float* small[5] = {nullptr, nullptr, nullptr, nullptr, nullptr};
    int nsmall = 0;
    for (int i = 0; i < n_in; ++i) {
        switch (in_sizes[i]) {
            case 32768:    latent = (const float*)d_in[i]; break;
            case 5000:
            case 10000:    genes  = (const int*)d_in[i];   break;
            case 2048:     W1     = (const float*)d_in[i]; break;
            case 40960000: lw     = (const float*)d_in[i]; break;
            case 640000:   rw     = (const float*)d_in[i]; break;
            case 32: if (nsmall < 5) small[nsmall++] = (const float*)d_in[i]; break;
            default: break;
        }
    }
    if (!latent || !genes || !W1 || !lw || !rw || nsmall < 5) return;
    const float* b1v   = small[0];
    const float* gamma = small[1];
    const float* beta  = small[2];
    const float* mean  = small[3];
    const float* var   = small[4];

    float* hbuf = (float*)d_ws;                                    // 64 KB fp32 h
    unsigned short* hbf = (unsigned short*)((char*)d_ws + 65536);  // 32 KB bf16 h
    float* logit_out = (float*)d_out;                              // [512,5000,64]
    float* rho_out   = logit_out + (size_t)B_SZ * G_OI_N * K_SZ;   // [512,5000]

    mlp_kernel<<<(B_SZ * H_SZ) / 256, 256, 0, stream>>>(latent, W1, b1v, gamma, beta,
                                                        mean, var, hbuf, hbf);
    logit_rho_kernel<<<2 * NCHUNK + RHO_BLOCKS, 256, 0, stream>>>(
        hbf, genes, lw, logit_out, hbuf, rw, rho_out);
}

// Round 20
// 154.608 us; speedup vs baseline: 1.0660x; 1.0660x over previous
//
#include <hip/hip_runtime.h>
#include <hip/hip_bf16.h>
#include <cstdint>

#define B_SZ   512
#define NLAT   64
#define H_SZ   32
#define G_OI_N 5000
#define K_SZ   64

#define NCHUNK 1250   // chunks of 4 genes (one per wave); logit blocks = 2*NCHUNK
#define RHO_BLOCKS 320

typedef __attribute__((ext_vector_type(8))) short short8v;   // 8 x bf16
typedef __attribute__((ext_vector_type(4))) float float4v;

__device__ __forceinline__ unsigned short f2bf(float x) {
    union { float f; unsigned u; } v; v.f = x;
    unsigned r = v.u + 0x7fff + ((v.u >> 16) & 1);            // RTNE
    return (unsigned short)(r >> 16);
}

// ---------------- Kernel A: h = BN(relu(latent @ W1 + b1))
__global__ __launch_bounds__(256) void mlp_kernel(
    const float* __restrict__ latent, const float* __restrict__ W1,
    const float* __restrict__ b1, const float* __restrict__ gamma,
    const float* __restrict__ beta, const float* __restrict__ mean,
    const float* __restrict__ var, float* __restrict__ hout,
    unsigned short* __restrict__ hbf)
{
    int idx = blockIdx.x * 256 + threadIdx.x;   // 0..16383 = b*32 + j
    int b = idx >> 5;
    int j = idx & 31;
    float acc = 0.f;
    const float4* lp = reinterpret_cast<const float4*>(latent + b * NLAT);
#pragma unroll
    for (int q = 0; q < NLAT / 4; ++q) {
        float4 lv = lp[q];
        acc = fmaf(lv.x, W1[(4 * q + 0) * H_SZ + j], acc);
        acc = fmaf(lv.y, W1[(4 * q + 1) * H_SZ + j], acc);
        acc = fmaf(lv.z, W1[(4 * q + 2) * H_SZ + j], acc);
        acc = fmaf(lv.w, W1[(4 * q + 3) * H_SZ + j], acc);
    }
    acc += b1[j];
    acc = fmaxf(acc, 0.f);
    acc = gamma[j] * (acc - mean[j]) * rsqrtf(var[j] + 1e-5f) + beta[j];
    hout[idx] = acc;
    hbf[idx]  = f2bf(acc);
}

// ---------------- Kernel B+C fused (exact r18 champion, 155.6 µs):
// blocks [0, 2*NCHUNK) = v9 logit (gene-per-wave, private-LDS transpose,
// zero barriers, bh = blockIdx LSB); blocks [2*NCHUNK, +320) = coalesced rho
// filling logit's CU-tail bubbles.
__global__ __launch_bounds__(256) void logit_rho_kernel(
    const unsigned short* __restrict__ hbf, const int* __restrict__ genes,
    const float* __restrict__ lw, float* __restrict__ out,
    const float* __restrict__ hbuf, const float* __restrict__ rw,
    float* __restrict__ rho_out)
{
    __shared__ float lt[4 * 1024];             // 4 waves x 4KB private tiles

    if (blockIdx.x >= 2 * NCHUNK) {
        // ---------- rho path: rho[b,g] = sum_h h[b,h] * rw[genes[g],h]
        const int rb = blockIdx.x - 2 * NCHUNK;   // 0..319
        const int gx = rb % 20;
        const int bx = rb / 20;
        const int g = gx * 256 + threadIdx.x;
        if (g >= G_OI_N) return;
        const size_t gene = (size_t)genes[g];

        float rreg[H_SZ];
        const float4* rp = reinterpret_cast<const float4*>(rw + gene * H_SZ);
#pragma unroll
        for (int q = 0; q < 8; ++q) {
            float4 rv = rp[q];
            rreg[4 * q + 0] = rv.x; rreg[4 * q + 1] = rv.y;
            rreg[4 * q + 2] = rv.z; rreg[4 * q + 3] = rv.w;
        }
        const int b0 = bx * 32;
        for (int b = b0; b < b0 + 32; ++b) {
            const float4* hp = reinterpret_cast<const float4*>(hbuf + b * H_SZ);
            float a0 = 0.f, a1 = 0.f, a2 = 0.f, a3 = 0.f;
#pragma unroll
            for (int q = 0; q < 8; ++q) {
                float4 hv = hp[q];
                a0 = fmaf(hv.x, rreg[4 * q + 0], a0);
                a1 = fmaf(hv.y, rreg[4 * q + 1], a1);
                a2 = fmaf(hv.z, rreg[4 * q + 2], a2);
                a3 = fmaf(hv.w, rreg[4 * q + 3], a3);
            }
            rho_out[(size_t)b * G_OI_N + g] = (a0 + a1) + (a2 + a3);
        }
        return;
    }

    // ---------- logit path (v9, unchanged): gene-per-wave, private-LDS
    // transpose epilogue, zero barriers. bh = blockIdx LSB (r18 optimum).
    const int bh    = blockIdx.x & 1;          // 256-row half
    const int chunk = blockIdx.x >> 1;         // 0..1249
    const int lane  = threadIdx.x & 63;
    const int w     = threadIdx.x >> 6;        // wave -> own gene
    const int row16 = lane & 15;
    const int kg    = lane >> 4;               // 0..3
    const int b0    = bh * 256;
    char* wt = reinterpret_cast<char*>(lt + w * 1024);

    const int g = chunk * 4 + w;
    const size_t gene = (size_t)genes[g];

    // A-operand (lw): own gene, all 4 kt — loaded once (32 dwords/lane).
    short8v afr[4];
    {
        const float* ap = lw + gene * (size_t)(H_SZ * K_SZ)
                             + (size_t)(kg * 8) * K_SZ + row16;
#pragma unroll
        for (int kt = 0; kt < 4; ++kt)
#pragma unroll
            for (int j = 0; j < 8; ++j)
                afr[kt][j] = (short)f2bf(ap[kt * 16 + (size_t)j * K_SZ]);
    }

    // B-operand (h): 16 m-tiles covering the 256-row half.
    short8v hfr[16];
#pragma unroll
    for (int mt = 0; mt < 16; ++mt)
        hfr[mt] = *reinterpret_cast<const short8v*>(
            hbf + (b0 + mt * 16 + row16) * H_SZ + kg * 8);

    const size_t GK = (size_t)G_OI_N * K_SZ;
    float* og = out + (size_t)g * K_SZ;
    for (int mt = 0; mt < 16; ++mt) {
        // 4 kt MFMAs -> wave-private swizzled LDS tile [16 b-rows][64 k]
#pragma unroll
        for (int kt = 0; kt < 4; ++kt) {
            float4v acc = {0.f, 0.f, 0.f, 0.f};
            acc = __builtin_amdgcn_mfma_f32_16x16x32_bf16(afr[kt], hfr[mt], acc, 0, 0, 0);
            int off = row16 * 256 + kt * 64 + kg * 16;
            off ^= (row16 & 7) << 4;
            *reinterpret_cast<float4v*>(wt + off) = acc;
        }
        // transposed read + store: each instr = 4 rows x 256B contiguous
#pragma unroll
        for (int r2 = 0; r2 < 4; ++r2) {
            const int rrow = 4 * r2 + kg;      // 0..15
            int roff = rrow * 256 + row16 * 16;
            roff ^= (rrow & 7) << 4;
            float4v v = *reinterpret_cast<const float4v*>(wt + roff);
            *reinterpret_cast<float4v*>(
                og + (size_t)(b0 + mt * 16 + rrow) * GK + row16 * 4) = v;
        }
    }
}

extern "C" void kernel_launch(void* const* d_in, const int* in_sizes, int n_in,
                              void* d_out, int out_size, void* d_ws, size_t ws_size,
                              hipStream_t stream)
{
    // Bind inputs by SIZE SIGNATURE (all sizes unique; robust to ordering).
    const float *latent = nullptr, *W1 = nullptr, *lw = nullptr, *rw = nullptr;
    const int* genes = nullptr;
    const float* small[5] = {nullptr, nullptr, nullptr, nullptr, nullptr};
    int nsmall = 0;
    for (int i = 0; i < n_in; ++i) {
        switch (in_sizes[i]) {
            case 32768:    latent = (const float*)d_in[i]; break;
            case 5000:
            case 10000:    genes  = (const int*)d_in[i];   break;
            case 2048:     W1     = (const float*)d_in[i]; break;
            case 40960000: lw     = (const float*)d_in[i]; break;
            case 640000:   rw     = (const float*)d_in[i]; break;
            case 32: if (nsmall < 5) small[nsmall++] = (const float*)d_in[i]; break;
            default: break;
        }
    }
    if (!latent || !genes || !W1 || !lw || !rw || nsmall < 5) return;
    const float* b1v   = small[0];
    const float* gamma = small[1];
    const float* beta  = small[2];
    const float* mean  = small[3];
    const float* var   = small[4];

    float* hbuf = (float*)d_ws;                                    // 64 KB fp32 h
    unsigned short* hbf = (unsigned short*)((char*)d_ws + 65536);  // 32 KB bf16 h
    float* logit_out = (float*)d_out;                              // [512,5000,64]
    float* rho_out   = logit_out + (size_t)B_SZ * G_OI_N * K_SZ;   // [512,5000]

    mlp_kernel<<<(B_SZ * H_SZ) / 256, 256, 0, stream>>>(latent, W1, b1v, gamma, beta,
                                                        mean, var, hbuf, hbf);
    logit_rho_kernel<<<2 * NCHUNK + RHO_BLOCKS, 256, 0, stream>>>(
        hbf, genes, lw, logit_out, hbuf, rw, rho_out);
}